// Round 1
// baseline (311.960 us; speedup 1.0000x reference)
//
#include <hip/hip_runtime.h>
#include <hip/hip_bf16.h>

#define LL 4
#define NN 50000
#define DD 64
#define EE 500000
#define HID 256
#define KDIM 512
#define LN_EPS 1e-5f

typedef __bf16 bf16x8 __attribute__((ext_vector_type(8)));
typedef float f32x4 __attribute__((ext_vector_type(4)));

// ---------- kernel 1: t[l,n,d] = bf16( tanh( imp_l * h[l,n,d] ) ) ----------
__global__ void tanh_conv(const float* __restrict__ h, __bf16* __restrict__ t) {
    int i = (blockIdx.x * 256 + threadIdx.x) * 8;          // 12.8M elems, 8/thread
    int l = i / (NN * DD);                                  // const-divide (magic mul)
    float imp = (float)(l + 1) * 0.1f;                      // [1,2,3,4]/10
    const float4* p = (const float4*)(h + i);
    float4 a = p[0];
    float4 b = p[1];
    bf16x8 r;
    r[0] = (__bf16)tanhf(imp * a.x);
    r[1] = (__bf16)tanhf(imp * a.y);
    r[2] = (__bf16)tanhf(imp * a.z);
    r[3] = (__bf16)tanhf(imp * a.w);
    r[4] = (__bf16)tanhf(imp * b.x);
    r[5] = (__bf16)tanhf(imp * b.y);
    r[6] = (__bf16)tanhf(imp * b.z);
    r[7] = (__bf16)tanhf(imp * b.w);
    *(bf16x8*)(t + i) = r;
}

// ---------- kernel 2: W1 (256x512 f32) -> bf16, chunked [kc][h][32] ----------
__global__ void w1_conv(const float* __restrict__ w1, __bf16* __restrict__ o) {
    int t = blockIdx.x * 256 + threadIdx.x;                 // 4096 threads
    int h = t >> 4;
    int kc = t & 15;
    const float4* p = (const float4*)(w1 + h * KDIM + kc * 32);
    bf16x8 r[4];
    #pragma unroll
    for (int j = 0; j < 8; ++j) {
        float4 v = p[j];
        r[j >> 1][(j & 1) * 4 + 0] = (__bf16)v.x;
        r[j >> 1][(j & 1) * 4 + 1] = (__bf16)v.y;
        r[j >> 1][(j & 1) * 4 + 2] = (__bf16)v.z;
        r[j >> 1][(j & 1) * 4 + 3] = (__bf16)v.w;
    }
    bf16x8* q = (bf16x8*)(o + ((size_t)kc * 256 + h) * 32);
    q[0] = r[0]; q[1] = r[1]; q[2] = r[2]; q[3] = r[3];
}

// ---------- kernel 3: gather + GEMM(512x256, bf16 MFMA) + LN + ReLU + dot ----------
// WG = 256 threads (4 waves). 64 edges per WG; wave w owns edges [w*16, w*16+16)
// x all 256 hid columns (16 MFMA tiles of 16x16x32).
#define APAD 40   // row stride in bf16: 32 + 8 pad -> 2-way bank aliasing only (free)

__global__ __launch_bounds__(256, 4)
void edge_mlp(const __bf16* __restrict__ tb, const __bf16* __restrict__ w1c,
              const int* __restrict__ src, const int* __restrict__ dst,
              const float* __restrict__ b1, const float* __restrict__ w3,
              const float* __restrict__ b3, const float* __restrict__ gamma,
              const float* __restrict__ beta, float* __restrict__ out) {
    __shared__ __bf16 A_lds[64 * APAD];     // 64 edges x 32 k (padded)
    __shared__ __bf16 B_lds[256 * APAD];    // 256 hid x 32 k (padded)
    __shared__ int   idx_lds[128];          // [0..63]=src nodes, [64..127]=dst nodes
    __shared__ float eb[4 * 256];           // b1 | gamma | beta | w3

    const int tid = threadIdx.x;
    const int e0 = blockIdx.x * 64;

    if (tid < 64) {
        int e = e0 + tid;
        idx_lds[tid] = (e < EE) ? src[e] : 0;
    } else if (tid < 128) {
        int e = e0 + tid - 64;
        idx_lds[tid] = (e < EE) ? dst[e] : 0;
    }
    eb[tid]       = b1[tid];
    eb[256 + tid] = gamma[tid];
    eb[512 + tid] = beta[tid];
    eb[768 + tid] = w3[tid];
    __syncthreads();

    // fixed gather role: this thread always serves edge eL, 16B piece `piece`
    const int eL    = tid >> 2;
    const int piece = tid & 3;
    const int nsrc  = idx_lds[eL];
    const int ndst  = idx_lds[64 + eL];

    const int lane = tid & 63;
    const int wave = tid >> 6;
    const int q    = lane >> 4;   // quad
    const int c    = lane & 15;   // col within tile

    f32x4 acc[16];
    #pragma unroll
    for (int i = 0; i < 16; ++i) acc[i] = (f32x4){0.f, 0.f, 0.f, 0.f};

    // prefetch chunk 0 into registers
    uint4 aReg, bReg0, bReg1, bReg2, bReg3;
    {
        aReg = *(const uint4*)(tb + (size_t)nsrc * DD + piece * 8);   // l=0, src half, c0=0
        const uint4* gb = (const uint4*)(w1c + (size_t)tid * 32);
        bReg0 = gb[0]; bReg1 = gb[1]; bReg2 = gb[2]; bReg3 = gb[3];
    }

    for (int kc = 0; kc < 16; ++kc) {
        // commit prefetched chunk to LDS
        *(uint4*)(&A_lds[eL * APAD + piece * 8]) = aReg;
        {
            uint4* bw = (uint4*)(&B_lds[tid * APAD]);
            bw[0] = bReg0; bw[1] = bReg1;
            *(uint4*)(&B_lds[tid * APAD + 16]) = bReg2;
            *(uint4*)(&B_lds[tid * APAD + 24]) = bReg3;
        }
        __syncthreads();

        // prefetch next chunk (overlaps MFMA below)
        if (kc < 15) {
            int k0 = (kc + 1) * 32;
            int l    = k0 >> 7;          // layer
            int half = (k0 >> 6) & 1;    // 0=src, 1=dst
            int c0   = k0 & 63;          // 0 or 32
            int node = half ? ndst : nsrc;
            aReg = *(const uint4*)(tb + ((size_t)l * NN + node) * DD + c0 + piece * 8);
            const uint4* gb = (const uint4*)(w1c + ((size_t)(kc + 1) * 256 + tid) * 32);
            bReg0 = gb[0]; bReg1 = gb[1]; bReg2 = gb[2]; bReg3 = gb[3];
        }

        // A-frag: m = lane&15 within this wave's 16-edge subtile, k = quad*8..+8
        bf16x8 af = *(const bf16x8*)(&A_lds[(wave * 16 + c) * APAD + q * 8]);
        #pragma unroll
        for (int nt = 0; nt < 16; ++nt) {
            bf16x8 bf = *(const bf16x8*)(&B_lds[(nt * 16 + c) * APAD + q * 8]);
            acc[nt] = __builtin_amdgcn_mfma_f32_16x16x32_bf16(af, bf, acc[nt], 0, 0, 0);
        }
        __syncthreads();
    }

    // ---- epilogue: LN + ReLU + dot(w3), all within the wave ----
    // C/D layout: col(hid%16) = lane&15, row(edge%16) = quad*4 + reg.
    // This lane holds, for edges m = q*4+r (r=0..3), hid values {nt*16+c}.
    float sum[4] = {0.f, 0.f, 0.f, 0.f};
    float sq[4]  = {0.f, 0.f, 0.f, 0.f};
    #pragma unroll
    for (int nt = 0; nt < 16; ++nt) {
        float bb = eb[nt * 16 + c];
        #pragma unroll
        for (int r = 0; r < 4; ++r) {
            float v = acc[nt][r] + bb;
            sum[r] += v;
            sq[r]   = fmaf(v, v, sq[r]);
        }
    }
    #pragma unroll
    for (int m = 1; m < 16; m <<= 1) {
        #pragma unroll
        for (int r = 0; r < 4; ++r) {
            sum[r] += __shfl_xor(sum[r], m);
            sq[r]  += __shfl_xor(sq[r],  m);
        }
    }
    float mu[4], rs[4];
    #pragma unroll
    for (int r = 0; r < 4; ++r) {
        mu[r] = sum[r] * (1.0f / 256.0f);
        float var = sq[r] * (1.0f / 256.0f) - mu[r] * mu[r];
        rs[r] = rsqrtf(var + LN_EPS);
    }
    float dot[4] = {0.f, 0.f, 0.f, 0.f};
    #pragma unroll
    for (int nt = 0; nt < 16; ++nt) {
        int hh   = nt * 16 + c;
        float bb = eb[hh];
        float g  = eb[256 + hh];
        float bt = eb[512 + hh];
        float w  = eb[768 + hh];
        #pragma unroll
        for (int r = 0; r < 4; ++r) {
            float v = acc[nt][r] + bb;
            float y = (v - mu[r]) * rs[r] * g + bt;
            y = fmaxf(y, 0.0f);
            dot[r] = fmaf(y, w, dot[r]);
        }
    }
    #pragma unroll
    for (int m = 1; m < 16; m <<= 1) {
        #pragma unroll
        for (int r = 0; r < 4; ++r) dot[r] += __shfl_xor(dot[r], m);
    }
    if (c == 0) {
        float b3v = b3[0];
        #pragma unroll
        for (int r = 0; r < 4; ++r) {
            int e = e0 + wave * 16 + q * 4 + r;
            if (e < EE) out[e] = dot[r] + b3v;
        }
    }
}

extern "C" void kernel_launch(void* const* d_in, const int* in_sizes, int n_in,
                              void* d_out, int out_size, void* d_ws, size_t ws_size,
                              hipStream_t stream) {
    const float* h_all  = (const float*)d_in[0];
    const int*   src    = (const int*)  d_in[1];
    const int*   dst    = (const int*)  d_in[2];
    const float* W1     = (const float*)d_in[3];
    const float* b1     = (const float*)d_in[4];
    const float* W3     = (const float*)d_in[5];
    const float* b3     = (const float*)d_in[6];
    const float* gamma2 = (const float*)d_in[7];
    const float* beta2  = (const float*)d_in[8];
    float* out = (float*)d_out;

    __bf16* tb  = (__bf16*)d_ws;                       // 12.8M bf16 = 25.6 MB
    __bf16* w1c = tb + (size_t)LL * NN * DD;           // 131072 bf16 = 256 KB

    tanh_conv<<<6250, 256, 0, stream>>>(h_all, tb);    // 6250*256*8 = 12.8M exact
    w1_conv<<<16, 256, 0, stream>>>(W1, w1c);          // 16*256 = 4096 threads
    edge_mlp<<<(EE + 63) / 64, 256, 0, stream>>>(tb, w1c, src, dst,
                                                 b1, W3, b3, gamma2, beta2, out);
}